// Round 13
// baseline (92.588 us; speedup 1.0000x reference)
//
#include <hip/hip_runtime.h>
#include <stdint.h>

// GINConv1d: B=4, N=8192, K=16, C_IN=C_OUT=128
//
// R12 (90.18, best): cost model 3-for-3 (lane-req + line-touch). R13 attacks
// the two remaining non-minimized terms:
//  1) scalar out stores (8192 lane-req/block ~ the whole gather!) -> stage acc
//     in padded LDS out_s[32][132], then 4x f32x4 coalesced nt-stores/thread
//     (1024B contiguous per wave-instr).
//  2) cvt producer-XCD != consumer-XCD: swizzle cvt's gid so batch b's xb is
//     converted ON XCD pair {2b,2b+1} where the gather will read it (dirty
//     lines land in the right L2).
#define BATCH   4
#define NNODE   8192
#define KNBR    16
#define CIN     128
#define COUT    128
#define MB      32          // rows (nodes) per block -> 1024 blocks
#define THREADS 256
#define HS_STRIDE 136       // shorts per h_s row: 128 + 8 pad
#define OS_STRIDE 132       // floats per out_s row: 128 + 4 pad

#define XELEM   (BATCH * NNODE * CIN)          // 4194304 fp32 elements
#define WELEM   (COUT * CIN)                   // 16384 fp32 elements
#define CVT_XBLK (XELEM / (256 * 8))           // 2048 blocks for x
#define CVT_WBLK (WELEM / (256 * 8))           // 8 blocks for W

typedef __attribute__((ext_vector_type(8))) short short8;   // 8 bf16 (MFMA A/B frag)
typedef __attribute__((ext_vector_type(4))) float f32x4;
typedef __attribute__((ext_vector_type(4))) int   i32x4;
typedef __attribute__((ext_vector_type(2))) int   i32x2;

__device__ __forceinline__ short bf16_rne(float f) {
    union { float f; uint32_t u; } v; v.f = f;
    return (short)((v.u + 0x7FFFu + ((v.u >> 16) & 1u)) >> 16);  // round-to-nearest-even
}
__device__ __forceinline__ float bf16_f32(short s) {
    union { uint32_t u; float f; } v; v.u = ((uint32_t)(uint16_t)s) << 16;
    return v.f;
}

// ---------------- prepass: {x, W} fp32 -> bf16 in workspace ------------------------
// x-part gid is XCD-swizzled: block bi runs on XCD (bi&7); batch b = (bi&7)>>1,
// so batch b's xb is produced (left dirty in L2) on XCD pair {2b,2b+1} — the
// same pair that gathers it in gin_fused.
__global__ __launch_bounds__(256)
void cvt_bf16(const float* __restrict__ x, const float* __restrict__ W,
              ushort* __restrict__ xb) {
    const int bi = blockIdx.x;
    const float* src;
    ushort*      dst;
    int          gid;
    if (bi < CVT_XBLK) {
        const int xcd = bi & 7;
        const int sub = bi >> 3;                 // 0..255
        const int b   = xcd >> 1;                // batch 0..3
        const int u   = ((xcd & 1) << 8) | sub;  // 0..511 unit within batch
        src = x; dst = xb;
        gid = (b * 512 + u) * 256 + threadIdx.x;
    } else {
        src = W; dst = xb + XELEM;
        gid = (bi - CVT_XBLK) * 256 + threadIdx.x;
    }
    const f32x4* xp = (const f32x4*)src + (size_t)gid * 2;
    f32x4 a = __builtin_nontemporal_load(xp);        // fp32 source is dead after this
    f32x4 c = __builtin_nontemporal_load(xp + 1);
    short8 s;
    s[0]=bf16_rne(a[0]); s[1]=bf16_rne(a[1]); s[2]=bf16_rne(a[2]); s[3]=bf16_rne(a[3]);
    s[4]=bf16_rne(c[0]); s[5]=bf16_rne(c[1]); s[6]=bf16_rne(c[2]); s[7]=bf16_rne(c[3]);
    ((short8*)dst)[gid] = s;
}

// ---------------- fused gather + eps-residual + MFMA GEMM + bias + ReLU ------------
// launch_bounds(256,2): VGPR cap 256 so all 32 neighbor prefetch loads (128 data
// VGPRs) stay in flight without spilling.
template<bool USEBF>
__global__ __launch_bounds__(THREADS, 2)
void gin_fused(const float*  __restrict__ x,      // [B,N,CIN] fp32
               const ushort* __restrict__ xb,     // [B,N,CIN] bf16 (if USEBF)
               const ushort* __restrict__ wb,     // [COUT,CIN] bf16 (if USEBF)
               const int*    __restrict__ eidx,   // [2,B,N,K] int32; plane 0 = source idx
               const float*  __restrict__ W,      // [COUT,CIN] fp32
               const float*  __restrict__ bias,   // [COUT] fp32
               const float*  __restrict__ epsp,   // [1] fp32
               float*        __restrict__ out)    // [B,N,COUT] fp32
{
    __shared__ __align__(16) short h_s[MB * HS_STRIDE];
    __shared__ __align__(16) int   idx_s[MB * KNBR];     // 2 KB
    __shared__ __align__(16) float out_s[MB * OS_STRIDE];// 16.5 KB

    const int tid = threadIdx.x;
    // XCD-locality swizzle: blockIdx -> XCD round-robin (i & 7). Pin batch b to
    // XCDs {2b,2b+1} so each XCD's gather set = one batch (2 MiB bf16) -> L2-resident.
    const int i   = blockIdx.x;            // 0..1023
    const int xcd = i & 7;
    const int sub = i >> 3;                // 0..127
    const int b   = xcd >> 1;              // batch 0..3
    const int wbi = ((xcd & 1) << 7) | sub;// 0..255 within batch
    const int n0  = wbi * MB;
    const int row0 = b * NNODE + n0;

    const float eps1 = 1.0f + epsp[0];

    // ---------------- Phase 0: stage block's indices via LDS (coalesced once) ------
    {
        const i32x2* src = (const i32x2*)(eidx + ((size_t)b * NNODE + n0) * KNBR);
        i32x2 v = __builtin_nontemporal_load(src + tid);
        *(i32x2*)(idx_s + tid * 2) = v;
    }
    __syncthreads();

    // ---------------- Phase A: gather + sum -> h_s (bf16) --------------------------
    {
        const int r  = tid >> 3;           // row within block, 0..31
        const int q  = tid & 7;            // slice index, 0..7
        const int n  = n0 + r;
        // Line-split slices: A = shorts [q*8, q*8+8)   -> bytes [q*16, +16): LINE 0
        //                    B = shorts [64+q*8, ...)  -> bytes [128+q*16): LINE 1
        const int cA = q * 8;
        const int cB = 64 + q * 8;

        int js[KNBR];
        {
            // same-address across the 8 q-threads of a row -> LDS broadcast (free)
            const i32x4* jp = (const i32x4*)(idx_s + r * KNBR);
            #pragma unroll
            for (int p = 0; p < 4; ++p) {
                i32x4 jv = jp[p];
                js[p*4+0]=jv.x; js[p*4+1]=jv.y; js[p*4+2]=jv.z; js[p*4+3]=jv.w;
            }
        }

        float acc[16];

        if constexpr (USEBF) {
            const ushort* xbb = xb + (size_t)b * NNODE * CIN;
            const ushort* xs  = xbb + (size_t)n * CIN;
            short8 s0 = *(const short8*)(xs + cA), s1 = *(const short8*)(xs + cB);

            // Prefetch ALL 16 neighbor slices into registers (32 x 16B loads in
            // flight per thread) BEFORE any accumulation -> memory-level parallelism.
            short8 t0[KNBR], t1[KNBR];
            #pragma unroll
            for (int k = 0; k < KNBR; ++k) {
                const ushort* xn = xbb + (size_t)js[k] * CIN;
                t0[k] = *(const short8*)(xn + cA);
                t1[k] = *(const short8*)(xn + cB);
            }

            #pragma unroll
            for (int e = 0; e < 8; ++e) {
                acc[e]     = eps1 * bf16_f32(s0[e]);
                acc[8 + e] = eps1 * bf16_f32(s1[e]);
            }
            #pragma unroll
            for (int k = 0; k < KNBR; ++k) {
                #pragma unroll
                for (int e = 0; e < 8; ++e) {
                    acc[e]     += bf16_f32(t0[k][e]);
                    acc[8 + e] += bf16_f32(t1[k][e]);
                }
            }
        } else {
            const float* xbb = x + (size_t)b * NNODE * CIN;
            const float* xs  = xbb + (size_t)n * CIN;
            #pragma unroll
            for (int p = 0; p < 2; ++p) {
                f32x4 v0 = *(const f32x4*)(xs + (p ? cB : cA) + 0);
                f32x4 v1 = *(const f32x4*)(xs + (p ? cB : cA) + 4);
                #pragma unroll
                for (int e = 0; e < 4; ++e) {
                    acc[p*8+e]   = eps1 * v0[e];
                    acc[p*8+4+e] = eps1 * v1[e];
                }
            }
            #pragma unroll
            for (int k = 0; k < KNBR; ++k) {
                const float* xn = xbb + (size_t)js[k] * CIN;
                #pragma unroll
                for (int p = 0; p < 2; ++p) {
                    f32x4 v0 = *(const f32x4*)(xn + (p ? cB : cA) + 0);
                    f32x4 v1 = *(const f32x4*)(xn + (p ? cB : cA) + 4);
                    #pragma unroll
                    for (int e = 0; e < 4; ++e) {
                        acc[p*8+e]   += v0[e];
                        acc[p*8+4+e] += v1[e];
                    }
                }
            }
        }

        short* hp = h_s + r * HS_STRIDE;
        {
            short8 sA, sB;
            #pragma unroll
            for (int e = 0; e < 8; ++e) {
                sA[e] = bf16_rne(acc[e]);
                sB[e] = bf16_rne(acc[8 + e]);
            }
            *(short8*)(hp + cA) = sA;
            *(short8*)(hp + cB) = sB;
        }
    }

    // ---------------- W -> bf16 B-fragments in registers (per-wave 32-out slice) ---
    const int wave = tid >> 6;
    const int lane = tid & 63;
    const int l16  = lane & 15;
    const int lq   = lane >> 4;            // quad 0..3

    short8 bfrag[2][4];                    // [o_tile][kb]: B[k][n]=W[o][c], n=l16, k=lq*8+j
    if constexpr (USEBF) {
        #pragma unroll
        for (int t = 0; t < 2; ++t) {
            const ushort* wp = wb + (size_t)(wave * 32 + t * 16 + l16) * CIN;
            #pragma unroll
            for (int kb = 0; kb < 4; ++kb)
                bfrag[t][kb] = *(const short8*)(wp + kb * 32 + lq * 8);
        }
    } else {
        #pragma unroll
        for (int t = 0; t < 2; ++t) {
            const float* wp = W + (size_t)(wave * 32 + t * 16 + l16) * CIN;
            #pragma unroll
            for (int kb = 0; kb < 4; ++kb) {
                const float* wq = wp + kb * 32 + lq * 8;
                f32x4 f0 = *(const f32x4*)(wq);
                f32x4 f1 = *(const f32x4*)(wq + 4);
                short8 s;
                s[0]=bf16_rne(f0[0]); s[1]=bf16_rne(f0[1]); s[2]=bf16_rne(f0[2]); s[3]=bf16_rne(f0[3]);
                s[4]=bf16_rne(f1[0]); s[5]=bf16_rne(f1[1]); s[6]=bf16_rne(f1[2]); s[7]=bf16_rne(f1[3]);
                bfrag[t][kb] = s;
            }
        }
    }
    const float bias0 = bias[wave * 32 + l16];
    const float bias1 = bias[wave * 32 + 16 + l16];

    __syncthreads();

    // ---------------- Phase B: MFMA GEMM + bias + ReLU -> out_s --------------------
    #pragma unroll
    for (int rt = 0; rt < MB / 16; ++rt) {
        const short* ap = h_s + (rt * 16 + l16) * HS_STRIDE + lq * 8;
        short8 afrag[4];
        #pragma unroll
        for (int kb = 0; kb < 4; ++kb)
            afrag[kb] = *(const short8*)(ap + kb * 32);

        #pragma unroll
        for (int t = 0; t < 2; ++t) {
            f32x4 acc = { 0.f, 0.f, 0.f, 0.f };
            #pragma unroll
            for (int kb = 0; kb < 4; ++kb)
                acc = __builtin_amdgcn_mfma_f32_16x16x32_bf16(afrag[kb], bfrag[t][kb], acc, 0, 0, 0);

            const float bv  = t ? bias1 : bias0;
            const int   col = wave * 32 + t * 16 + l16;
            #pragma unroll
            for (int ii = 0; ii < 4; ++ii) {
                const int row = rt * 16 + lq * 4 + ii;   // C/D: row = quad*4 + reg
                float v = acc[ii] + bv;
                // 2-way LDS bank alias only (132-float stride) = free
                out_s[row * OS_STRIDE + col] = v > 0.f ? v : 0.f;
            }
        }
    }

    __syncthreads();

    // ---------------- coalesced out store: 4 x f32x4 per thread --------------------
    // Per wave-instr: 64 lanes x 16B = 1024B fully contiguous (2 adjacent rows).
    {
        float* outb = out + (size_t)row0 * COUT;
        #pragma unroll
        for (int ps = 0; ps < 4; ++ps) {
            const int it  = ps * 256 + tid;   // 0..1023
            const int row = it >> 5;          // 0..31
            const int c4  = it & 31;          // f32x4 column index
            f32x4 v = *(const f32x4*)(out_s + row * OS_STRIDE + c4 * 4);
            // nt store: the 16 MiB out stream must not evict the bf16 gather set
            __builtin_nontemporal_store(v, (f32x4*)(outb + (size_t)row * COUT + c4 * 4));
        }
    }
}

extern "C" void kernel_launch(void* const* d_in, const int* in_sizes, int n_in,
                              void* d_out, int out_size, void* d_ws, size_t ws_size,
                              hipStream_t stream) {
    const float* x    = (const float*)d_in[0];
    const int*   eidx = (const int*)d_in[1];
    const float* W    = (const float*)d_in[2];
    const float* bias = (const float*)d_in[3];
    const float* eps  = (const float*)d_in[4];
    float*       out  = (float*)d_out;

    const size_t need = (size_t)(XELEM + WELEM) * sizeof(ushort);  // 8 MiB + 32 KiB
    dim3 grid((BATCH * NNODE) / MB);   // 1024 blocks

    if (ws_size >= need) {
        ushort* xb = (ushort*)d_ws;
        cvt_bf16<<<dim3(CVT_XBLK + CVT_WBLK), dim3(256), 0, stream>>>(x, W, xb);
        gin_fused<true><<<grid, dim3(THREADS), 0, stream>>>(x, xb, xb + XELEM, eidx, W, bias, eps, out);
    } else {
        gin_fused<false><<<grid, dim3(THREADS), 0, stream>>>(x, nullptr, nullptr, eidx, W, bias, eps, out);
    }
}

// Round 14
// 92.143 us; speedup vs baseline: 1.0048x; 1.0048x over previous
//
#include <hip/hip_runtime.h>
#include <stdint.h>

// GINConv1d: B=4, N=8192, K=16, C_IN=C_OUT=128
//
// R13 post-mortem: out_s LDS store-staging regressed (+2.4us: extra barrier
// serialized wave epilogues, 16.9KB LDS round-trip, lost store/gather overlap).
// R14 = R12 exactly (best, 90.18) + ONLY the cvt producer-XCD swizzle: batch
// b's xb is converted on XCD pair {2b,2b+1} where gin_fused gathers it, so
// dirty lines land in the consumer's L2 (no cross-XCD dirty-line resolve).
#define BATCH   4
#define NNODE   8192
#define KNBR    16
#define CIN     128
#define COUT    128
#define MB      32          // rows (nodes) per block -> 1024 blocks
#define THREADS 256
#define HS_STRIDE 136       // shorts per h_s row: 128 + 8 pad

#define XELEM   (BATCH * NNODE * CIN)          // 4194304 fp32 elements
#define WELEM   (COUT * CIN)                   // 16384 fp32 elements
#define CVT_XBLK (XELEM / (256 * 8))           // 2048 blocks for x
#define CVT_WBLK (WELEM / (256 * 8))           // 8 blocks for W

typedef __attribute__((ext_vector_type(8))) short short8;   // 8 bf16 (MFMA A/B frag)
typedef __attribute__((ext_vector_type(4))) float f32x4;
typedef __attribute__((ext_vector_type(4))) int   i32x4;
typedef __attribute__((ext_vector_type(2))) int   i32x2;

__device__ __forceinline__ short bf16_rne(float f) {
    union { float f; uint32_t u; } v; v.f = f;
    return (short)((v.u + 0x7FFFu + ((v.u >> 16) & 1u)) >> 16);  // round-to-nearest-even
}
__device__ __forceinline__ float bf16_f32(short s) {
    union { uint32_t u; float f; } v; v.u = ((uint32_t)(uint16_t)s) << 16;
    return v.f;
}

// ---------------- prepass: {x, W} fp32 -> bf16 in workspace ------------------------
// x-part gid is XCD-swizzled: block bi runs on XCD (bi&7); batch b = (bi&7)>>1,
// so batch b's xb is produced (left dirty in L2) on XCD pair {2b,2b+1} — the
// same pair that gathers it in gin_fused.
__global__ __launch_bounds__(256)
void cvt_bf16(const float* __restrict__ x, const float* __restrict__ W,
              ushort* __restrict__ xb) {
    const int bi = blockIdx.x;
    const float* src;
    ushort*      dst;
    int          gid;
    if (bi < CVT_XBLK) {
        const int xcd = bi & 7;
        const int sub = bi >> 3;                 // 0..255
        const int b   = xcd >> 1;                // batch 0..3
        const int u   = ((xcd & 1) << 8) | sub;  // 0..511 unit within batch
        src = x; dst = xb;
        gid = (b * 512 + u) * 256 + threadIdx.x;
    } else {
        src = W; dst = xb + XELEM;
        gid = (bi - CVT_XBLK) * 256 + threadIdx.x;
    }
    const f32x4* xp = (const f32x4*)src + (size_t)gid * 2;
    f32x4 a = __builtin_nontemporal_load(xp);        // fp32 source is dead after this
    f32x4 c = __builtin_nontemporal_load(xp + 1);
    short8 s;
    s[0]=bf16_rne(a[0]); s[1]=bf16_rne(a[1]); s[2]=bf16_rne(a[2]); s[3]=bf16_rne(a[3]);
    s[4]=bf16_rne(c[0]); s[5]=bf16_rne(c[1]); s[6]=bf16_rne(c[2]); s[7]=bf16_rne(c[3]);
    ((short8*)dst)[gid] = s;
}

// ---------------- fused gather + eps-residual + MFMA GEMM + bias + ReLU ------------
// launch_bounds(256,2): VGPR cap 256 so all 32 neighbor prefetch loads (128 data
// VGPRs) stay in flight without spilling.
template<bool USEBF>
__global__ __launch_bounds__(THREADS, 2)
void gin_fused(const float*  __restrict__ x,      // [B,N,CIN] fp32
               const ushort* __restrict__ xb,     // [B,N,CIN] bf16 (if USEBF)
               const ushort* __restrict__ wb,     // [COUT,CIN] bf16 (if USEBF)
               const int*    __restrict__ eidx,   // [2,B,N,K] int32; plane 0 = source idx
               const float*  __restrict__ W,      // [COUT,CIN] fp32
               const float*  __restrict__ bias,   // [COUT] fp32
               const float*  __restrict__ epsp,   // [1] fp32
               float*        __restrict__ out)    // [B,N,COUT] fp32
{
    __shared__ __align__(16) short h_s[MB * HS_STRIDE];
    __shared__ __align__(16) int   idx_s[MB * KNBR];     // 2 KB

    const int tid = threadIdx.x;
    // XCD-locality swizzle: blockIdx -> XCD round-robin (i & 7). Pin batch b to
    // XCDs {2b,2b+1} so each XCD's gather set = one batch (2 MiB bf16) -> L2-resident.
    const int i   = blockIdx.x;            // 0..1023
    const int xcd = i & 7;
    const int sub = i >> 3;                // 0..127
    const int b   = xcd >> 1;              // batch 0..3
    const int wbi = ((xcd & 1) << 7) | sub;// 0..255 within batch
    const int n0  = wbi * MB;
    const int row0 = b * NNODE + n0;

    const float eps1 = 1.0f + epsp[0];

    // ---------------- Phase 0: stage block's indices via LDS (coalesced once) ------
    {
        const i32x2* src = (const i32x2*)(eidx + ((size_t)b * NNODE + n0) * KNBR);
        i32x2 v = __builtin_nontemporal_load(src + tid);
        *(i32x2*)(idx_s + tid * 2) = v;
    }
    __syncthreads();

    // ---------------- Phase A: gather + sum -> h_s (bf16) --------------------------
    {
        const int r  = tid >> 3;           // row within block, 0..31
        const int q  = tid & 7;            // slice index, 0..7
        const int n  = n0 + r;
        // Line-split slices: A = shorts [q*8, q*8+8)   -> bytes [q*16, +16): LINE 0
        //                    B = shorts [64+q*8, ...)  -> bytes [128+q*16): LINE 1
        const int cA = q * 8;
        const int cB = 64 + q * 8;

        int js[KNBR];
        {
            // same-address across the 8 q-threads of a row -> LDS broadcast (free)
            const i32x4* jp = (const i32x4*)(idx_s + r * KNBR);
            #pragma unroll
            for (int p = 0; p < 4; ++p) {
                i32x4 jv = jp[p];
                js[p*4+0]=jv.x; js[p*4+1]=jv.y; js[p*4+2]=jv.z; js[p*4+3]=jv.w;
            }
        }

        float acc[16];

        if constexpr (USEBF) {
            const ushort* xbb = xb + (size_t)b * NNODE * CIN;
            const ushort* xs  = xbb + (size_t)n * CIN;
            short8 s0 = *(const short8*)(xs + cA), s1 = *(const short8*)(xs + cB);

            // Prefetch ALL 16 neighbor slices into registers (32 x 16B loads in
            // flight per thread) BEFORE any accumulation -> memory-level parallelism.
            short8 t0[KNBR], t1[KNBR];
            #pragma unroll
            for (int k = 0; k < KNBR; ++k) {
                const ushort* xn = xbb + (size_t)js[k] * CIN;
                t0[k] = *(const short8*)(xn + cA);
                t1[k] = *(const short8*)(xn + cB);
            }

            #pragma unroll
            for (int e = 0; e < 8; ++e) {
                acc[e]     = eps1 * bf16_f32(s0[e]);
                acc[8 + e] = eps1 * bf16_f32(s1[e]);
            }
            #pragma unroll
            for (int k = 0; k < KNBR; ++k) {
                #pragma unroll
                for (int e = 0; e < 8; ++e) {
                    acc[e]     += bf16_f32(t0[k][e]);
                    acc[8 + e] += bf16_f32(t1[k][e]);
                }
            }
        } else {
            const float* xbb = x + (size_t)b * NNODE * CIN;
            const float* xs  = xbb + (size_t)n * CIN;
            #pragma unroll
            for (int p = 0; p < 2; ++p) {
                f32x4 v0 = *(const f32x4*)(xs + (p ? cB : cA) + 0);
                f32x4 v1 = *(const f32x4*)(xs + (p ? cB : cA) + 4);
                #pragma unroll
                for (int e = 0; e < 4; ++e) {
                    acc[p*8+e]   = eps1 * v0[e];
                    acc[p*8+4+e] = eps1 * v1[e];
                }
            }
            #pragma unroll
            for (int k = 0; k < KNBR; ++k) {
                const float* xn = xbb + (size_t)js[k] * CIN;
                #pragma unroll
                for (int p = 0; p < 2; ++p) {
                    f32x4 v0 = *(const f32x4*)(xn + (p ? cB : cA) + 0);
                    f32x4 v1 = *(const f32x4*)(xn + (p ? cB : cA) + 4);
                    #pragma unroll
                    for (int e = 0; e < 4; ++e) {
                        acc[p*8+e]   += v0[e];
                        acc[p*8+4+e] += v1[e];
                    }
                }
            }
        }

        short* hp = h_s + r * HS_STRIDE;
        {
            short8 sA, sB;
            #pragma unroll
            for (int e = 0; e < 8; ++e) {
                sA[e] = bf16_rne(acc[e]);
                sB[e] = bf16_rne(acc[8 + e]);
            }
            *(short8*)(hp + cA) = sA;
            *(short8*)(hp + cB) = sB;
        }
    }

    // ---------------- W -> bf16 B-fragments in registers (per-wave 32-out slice) ---
    const int wave = tid >> 6;
    const int lane = tid & 63;
    const int l16  = lane & 15;
    const int lq   = lane >> 4;            // quad 0..3

    short8 bfrag[2][4];                    // [o_tile][kb]: B[k][n]=W[o][c], n=l16, k=lq*8+j
    if constexpr (USEBF) {
        #pragma unroll
        for (int t = 0; t < 2; ++t) {
            const ushort* wp = wb + (size_t)(wave * 32 + t * 16 + l16) * CIN;
            #pragma unroll
            for (int kb = 0; kb < 4; ++kb)
                bfrag[t][kb] = *(const short8*)(wp + kb * 32 + lq * 8);
        }
    } else {
        #pragma unroll
        for (int t = 0; t < 2; ++t) {
            const float* wp = W + (size_t)(wave * 32 + t * 16 + l16) * CIN;
            #pragma unroll
            for (int kb = 0; kb < 4; ++kb) {
                const float* wq = wp + kb * 32 + lq * 8;
                f32x4 f0 = *(const f32x4*)(wq);
                f32x4 f1 = *(const f32x4*)(wq + 4);
                short8 s;
                s[0]=bf16_rne(f0[0]); s[1]=bf16_rne(f0[1]); s[2]=bf16_rne(f0[2]); s[3]=bf16_rne(f0[3]);
                s[4]=bf16_rne(f1[0]); s[5]=bf16_rne(f1[1]); s[6]=bf16_rne(f1[2]); s[7]=bf16_rne(f1[3]);
                bfrag[t][kb] = s;
            }
        }
    }
    const float bias0 = bias[wave * 32 + l16];
    const float bias1 = bias[wave * 32 + 16 + l16];

    __syncthreads();

    // ---------------- Phase B: MFMA GEMM + bias + ReLU -----------------------------
    float* outb = out + (size_t)row0 * COUT;
    #pragma unroll
    for (int rt = 0; rt < MB / 16; ++rt) {
        const short* ap = h_s + (rt * 16 + l16) * HS_STRIDE + lq * 8;
        short8 afrag[4];
        #pragma unroll
        for (int kb = 0; kb < 4; ++kb)
            afrag[kb] = *(const short8*)(ap + kb * 32);

        #pragma unroll
        for (int t = 0; t < 2; ++t) {
            f32x4 acc = { 0.f, 0.f, 0.f, 0.f };
            #pragma unroll
            for (int kb = 0; kb < 4; ++kb)
                acc = __builtin_amdgcn_mfma_f32_16x16x32_bf16(afrag[kb], bfrag[t][kb], acc, 0, 0, 0);

            const float bv  = t ? bias1 : bias0;
            const int   col = wave * 32 + t * 16 + l16;
            #pragma unroll
            for (int ii = 0; ii < 4; ++ii) {
                const int row = rt * 16 + lq * 4 + ii;   // C/D: row = quad*4 + reg
                float v = acc[ii] + bv;
                v = v > 0.f ? v : 0.f;
                // nt store: the 16 MiB out stream must not evict the bf16 gather set
                __builtin_nontemporal_store(v, &outb[(size_t)row * COUT + col]);
            }
        }
    }
}

extern "C" void kernel_launch(void* const* d_in, const int* in_sizes, int n_in,
                              void* d_out, int out_size, void* d_ws, size_t ws_size,
                              hipStream_t stream) {
    const float* x    = (const float*)d_in[0];
    const int*   eidx = (const int*)d_in[1];
    const float* W    = (const float*)d_in[2];
    const float* bias = (const float*)d_in[3];
    const float* eps  = (const float*)d_in[4];
    float*       out  = (float*)d_out;

    const size_t need = (size_t)(XELEM + WELEM) * sizeof(ushort);  // 8 MiB + 32 KiB
    dim3 grid((BATCH * NNODE) / MB);   // 1024 blocks

    if (ws_size >= need) {
        ushort* xb = (ushort*)d_ws;
        cvt_bf16<<<dim3(CVT_XBLK + CVT_WBLK), dim3(256), 0, stream>>>(x, W, xb);
        gin_fused<true><<<grid, dim3(THREADS), 0, stream>>>(x, xb, xb + XELEM, eidx, W, bias, eps, out);
    } else {
        gin_fused<false><<<grid, dim3(THREADS), 0, stream>>>(x, nullptr, nullptr, eidx, W, bias, eps, out);
    }
}